// Round 1
// baseline (177.150 us; speedup 1.0000x reference)
//
#include <hip/hip_runtime.h>
#include <math.h>

// PRNN J2 plane-strain elastoplasticity scan.
// B=16384, T=128, F=3, MATPTS=16 (P=262144), O=3.
// Thread = (batch b, material point m). Block = 256 threads = 16 batches.
// x[b,:,:] staged to LDS once; per-step outputs overwrite the consumed x slot;
// one coalesced flush at the end. No barrier inside the T loop.

#define BLOCK 256
#define BPB 16          // batch elements per block
#define TSTEPS 128
#define ROWF (TSTEPS * 3)   // 384 floats per batch row
#define ROWP (ROWF + 1)     // padded LDS stride (breaks 4-way bank conflict)

__global__ __launch_bounds__(BLOCK, 4)
void prnn_j2_kernel(const float* __restrict__ x,
                    const float* __restrict__ W1,
                    const float* __restrict__ W2,
                    float* __restrict__ out)
{
    constexpr float MU    = (float)(3130.0 / (2.0 * (1.0 + 0.37)));
    constexpr float LAM   = (float)(3130.0 * 0.37 / ((1.0 + 0.37) * (1.0 - 2.0 * 0.37)));
    constexpr float SIG_Y = 64.8f;
    constexpr float H_ISO = 300.0f;
    const float TWO_MU  = 2.0f * MU;
    const float INV_DEN = 1.0f / (3.0f * MU + H_ISO);

    __shared__ float xs[BPB * ROWP];   // 16*385*4 = 24640 B

    const int tid = threadIdx.x;
    const int bl  = tid >> 4;     // local batch index 0..15
    const int m   = tid & 15;     // material point 0..15
    const int blockBase = blockIdx.x * (BPB * ROWF);

    // ---- stage x into LDS (coalesced global reads) ----
    for (int i = tid; i < BPB * ROWF; i += BLOCK) {
        int b = i / ROWF;
        int r = i - b * ROWF;
        xs[b * ROWP + r] = x[blockBase + i];
    }

    // ---- per-thread weights (tiny, broadcast through caches) ----
    float w1[3][3], w2s[3][3];
    #pragma unroll
    for (int c = 0; c < 3; ++c)
        #pragma unroll
        for (int f = 0; f < 3; ++f)
            w1[c][f] = W1[(3 * m + c) * 3 + f];
    #pragma unroll
    for (int o = 0; o < 3; ++o)
        #pragma unroll
        for (int c = 0; c < 3; ++c) {
            float w = W2[o * 48 + 3 * m + c];
            // stable softplus
            w2s[o][c] = fmaxf(w, 0.0f) + log1pf(expf(-fabsf(w)));
        }

    __syncthreads();

    float ep0 = 0.f, ep1 = 0.f, ep2 = 0.f, ep3 = 0.f, alpha = 0.f;
    float* xrow = &xs[bl * ROWP];

    for (int t = 0; t < TSTEPS; ++t) {
        const float x0 = xrow[t * 3 + 0];
        const float x1 = xrow[t * 3 + 1];
        const float x2 = xrow[t * 3 + 2];

        // fc1: per-point strain (exx, eyy, gamma_xy)
        const float e0 = w1[0][0] * x0 + w1[0][1] * x1 + w1[0][2] * x2;
        const float e1 = w1[1][0] * x0 + w1[1][1] * x1 + w1[1][2] * x2;
        const float e2 = w1[2][0] * x0 + w1[2][1] * x1 + w1[2][2] * x2;

        // elastic predictor
        const float ee_xx = e0 - ep0;
        const float ee_yy = e1 - ep1;
        const float ee_zz = -ep2;
        const float ee_xy = 0.5f * e2 - ep3;
        const float tr = ee_xx + ee_yy + ee_zz;
        const float lt = LAM * tr;
        const float sxx = lt + TWO_MU * ee_xx;
        const float syy = lt + TWO_MU * ee_yy;
        const float szz = lt + TWO_MU * ee_zz;
        const float sxy = TWO_MU * ee_xy;
        const float pm = (sxx + syy + szz) * (1.0f / 3.0f);
        const float dxx = sxx - pm, dyy = syy - pm, dzz = szz - pm;
        const float q = sqrtf(1.5f * (dxx * dxx + dyy * dyy + dzz * dzz
                                      + 2.0f * sxy * sxy));
        // radial return
        const float fy   = q - (SIG_Y + H_ISO * alpha);
        const float dgam = fmaxf(fy, 0.0f) * INV_DEN;
        const float qs   = fmaxf(q, 1e-12f);
        const float nsc  = 1.5f / qs;
        const float nxx = dxx * nsc, nyy = dyy * nsc, nzz = dzz * nsc, nxy = sxy * nsc;
        const float tmd = TWO_MU * dgam;
        const float s0 = sxx - tmd * nxx;
        const float s1 = syy - tmd * nyy;
        const float s2 = sxy - tmd * nxy;
        ep0 += dgam * nxx;
        ep1 += dgam * nyy;
        ep2 += dgam * nzz;
        ep3 += dgam * nxy;
        alpha += dgam;

        // fc2 partials (softplus weights)
        float o0 = w2s[0][0] * s0 + w2s[0][1] * s1 + w2s[0][2] * s2;
        float o1 = w2s[1][0] * s0 + w2s[1][1] * s1 + w2s[1][2] * s2;
        float o2 = w2s[2][0] * s0 + w2s[2][1] * s1 + w2s[2][2] * s2;

        // butterfly reduce across the 16 lanes of this batch's group
        #pragma unroll
        for (int off = 8; off >= 1; off >>= 1) {
            o0 += __shfl_xor(o0, off, 64);
            o1 += __shfl_xor(o1, off, 64);
            o2 += __shfl_xor(o2, off, 64);
        }
        // overwrite the consumed x slot with the output (lanes 0..2, one comp each)
        if (m < 3) {
            xrow[t * 3 + m] = (m == 0) ? o0 : (m == 1 ? o1 : o2);
        }
    }

    __syncthreads();

    // ---- coalesced flush LDS -> out ----
    for (int i = tid; i < BPB * ROWF; i += BLOCK) {
        int b = i / ROWF;
        int r = i - b * ROWF;
        out[blockBase + i] = xs[b * ROWP + r];
    }
}

extern "C" void kernel_launch(void* const* d_in, const int* in_sizes, int n_in,
                              void* d_out, int out_size, void* d_ws, size_t ws_size,
                              hipStream_t stream) {
    const float* x  = (const float*)d_in[0];
    const float* W1 = (const float*)d_in[1];
    const float* W2 = (const float*)d_in[2];
    float* out = (float*)d_out;

    const int B = 16384;
    dim3 grid(B / BPB);   // 1024 blocks
    dim3 block(BLOCK);
    prnn_j2_kernel<<<grid, block, 0, stream>>>(x, W1, W2, out);
}

// Round 2
// 141.600 us; speedup vs baseline: 1.2511x; 1.2511x over previous
//
#include <hip/hip_runtime.h>
#include <math.h>

// PRNN J2 plane-strain elastoplasticity scan.
// B=16384, T=128, F=3, MATPTS=16 (P=262144), O=3.
// Thread = (batch b, material point m). Block = 256 threads = 16 batches.
// x[b,:,:] staged to LDS once; per-step outputs overwrite the consumed x slot;
// one coalesced flush at the end. No barrier inside the T loop.
// R2: rsq instead of precise sqrt+div; DPP row-scan reduction instead of
// ds_bpermute shuffles; algebraic refold of the radial return.

#define BLOCK 256
#define BPB 16          // batch elements per block
#define TSTEPS 128
#define ROWF (TSTEPS * 3)   // 384 floats per batch row
#define ROWP (ROWF + 1)     // padded LDS stride

// fused DPP add: v += dpp_row_shr<N>(v), 0-filled at row edge (bound_ctrl=1)
#define DPP_ADD(v, ctrl)                                                     \
    v += __int_as_float(__builtin_amdgcn_update_dpp(                         \
        0, __float_as_int(v), (ctrl), 0xf, 0xf, true))
#define ROW_SHR(n) (0x110 + (n))

__global__ __launch_bounds__(BLOCK, 4)
void prnn_j2_kernel(const float* __restrict__ x,
                    const float* __restrict__ W1,
                    const float* __restrict__ W2,
                    float* __restrict__ out)
{
    constexpr float MU    = (float)(3130.0 / (2.0 * (1.0 + 0.37)));
    constexpr float LAM   = (float)(3130.0 * 0.37 / ((1.0 + 0.37) * (1.0 - 2.0 * 0.37)));
    constexpr float SIG_Y = 64.8f;
    constexpr float H_ISO = 300.0f;
    const float TWO_MU  = 2.0f * MU;
    const float K3MU    = 3.0f * MU;
    const float INV_DEN = 1.0f / (3.0f * MU + H_ISO);
    const float KBULK   = LAM + TWO_MU * (1.0f / 3.0f);   // pm = KBULK * tr
    const float C_Q2    = 6.0f * MU * MU;                 // q2 = C_Q2*(exd^2+eyd^2+ezd^2+2*exy^2)

    __shared__ float xs[BPB * ROWP];   // 16*385*4 = 24640 B

    const int tid = threadIdx.x;
    const int bl  = tid >> 4;     // local batch index 0..15
    const int m   = tid & 15;     // material point 0..15 == DPP row lane
    const int blockBase = blockIdx.x * (BPB * ROWF);

    // ---- stage x into LDS (coalesced global reads) ----
    for (int i = tid; i < BPB * ROWF; i += BLOCK) {
        int b = i / ROWF;
        int r = i - b * ROWF;
        xs[b * ROWP + r] = x[blockBase + i];
    }

    // ---- per-thread weights (tiny, broadcast through caches) ----
    float w1[3][3], w2s[3][3];
    #pragma unroll
    for (int c = 0; c < 3; ++c)
        #pragma unroll
        for (int f = 0; f < 3; ++f)
            w1[c][f] = W1[(3 * m + c) * 3 + f];
    #pragma unroll
    for (int o = 0; o < 3; ++o)
        #pragma unroll
        for (int c = 0; c < 3; ++c) {
            float w = W2[o * 48 + 3 * m + c];
            w2s[o][c] = fmaxf(w, 0.0f) + log1pf(expf(-fabsf(w)));  // stable softplus
        }

    __syncthreads();

    float p0 = 0.f, p1 = 0.f, p2 = 0.f, p3 = 0.f;
    float yld = SIG_Y;            // running yield threshold SIG_Y + H*alpha
    float* xrow = &xs[bl * ROWP];

    for (int t = 0; t < TSTEPS; ++t) {
        const float x0 = xrow[t * 3 + 0];
        const float x1 = xrow[t * 3 + 1];
        const float x2 = xrow[t * 3 + 2];

        // fc1: per-point strain (exx, eyy, gamma_xy)
        const float e0 = w1[0][0] * x0 + w1[0][1] * x1 + w1[0][2] * x2;
        const float e1 = w1[1][0] * x0 + w1[1][1] * x1 + w1[1][2] * x2;
        const float e2 = w1[2][0] * x0 + w1[2][1] * x1 + w1[2][2] * x2;

        // elastic strains (plane strain: ee_zz = -p2)
        const float ee_xx = e0 - p0;
        const float ee_yy = e1 - p1;
        const float ee_xy = fmaf(0.5f, e2, -p3);
        const float tr = (ee_xx + ee_yy) - p2;
        const float c3 = tr * (1.0f / 3.0f);
        // deviatoric elastic strains
        const float exd = ee_xx - c3;
        const float eyd = ee_yy - c3;
        const float ezd = -p2 - c3;
        // q^2 = 6 mu^2 (exd^2+eyd^2+ezd^2+2 exy^2)
        float u = exd * exd;
        u = fmaf(eyd, eyd, u);
        u = fmaf(ezd, ezd, u);
        const float t2 = ee_xy * ee_xy;
        u = fmaf(t2, 2.0f, u);
        const float q2 = fmaxf(C_Q2 * u, 1e-24f);
        const float rq = __builtin_amdgcn_rsqf(q2);  // 1/q
        const float q  = q2 * rq;                    // q

        const float fy   = q - yld;
        const float dgam = fmaxf(fy, 0.0f) * INV_DEN;
        yld = fmaf(H_ISO, dgam, yld);
        const float k   = K3MU * dgam * rq;          // = 2mu*dgam * 1.5/q
        const float omk = 1.0f - k;

        const float pm  = KBULK * tr;
        const float dxx = TWO_MU * exd;
        const float dyy = TWO_MU * eyd;
        const float sxy = TWO_MU * ee_xy;
        // corrected stresses
        const float s0 = fmaf(dxx, omk, pm);
        const float s1 = fmaf(dyy, omk, pm);
        const float s2 = sxy * omk;
        // plastic strain commit: dgam * n = k * (deviatoric elastic strain)
        p0 = fmaf(k, exd, p0);
        p1 = fmaf(k, eyd, p1);
        p2 = fmaf(k, ezd, p2);
        p3 = fmaf(k, ee_xy, p3);

        // fc2 partials (softplus weights)
        float o0 = w2s[0][0] * s0 + w2s[0][1] * s1 + w2s[0][2] * s2;
        float o1 = w2s[1][0] * s0 + w2s[1][1] * s1 + w2s[1][2] * s2;
        float o2 = w2s[2][0] * s0 + w2s[2][1] * s1 + w2s[2][2] * s2;

        // DPP inclusive row-scan sum across the 16-lane group; lane 15 = total
        DPP_ADD(o0, ROW_SHR(1)); DPP_ADD(o0, ROW_SHR(2));
        DPP_ADD(o0, ROW_SHR(4)); DPP_ADD(o0, ROW_SHR(8));
        DPP_ADD(o1, ROW_SHR(1)); DPP_ADD(o1, ROW_SHR(2));
        DPP_ADD(o1, ROW_SHR(4)); DPP_ADD(o1, ROW_SHR(8));
        DPP_ADD(o2, ROW_SHR(1)); DPP_ADD(o2, ROW_SHR(2));
        DPP_ADD(o2, ROW_SHR(4)); DPP_ADD(o2, ROW_SHR(8));

        if (m == 15) {
            xrow[t * 3 + 0] = o0;
            xrow[t * 3 + 1] = o1;
            xrow[t * 3 + 2] = o2;
        }
    }

    __syncthreads();

    // ---- coalesced flush LDS -> out ----
    for (int i = tid; i < BPB * ROWF; i += BLOCK) {
        int b = i / ROWF;
        int r = i - b * ROWF;
        out[blockBase + i] = xs[b * ROWP + r];
    }
}

extern "C" void kernel_launch(void* const* d_in, const int* in_sizes, int n_in,
                              void* d_out, int out_size, void* d_ws, size_t ws_size,
                              hipStream_t stream) {
    const float* x  = (const float*)d_in[0];
    const float* W1 = (const float*)d_in[1];
    const float* W2 = (const float*)d_in[2];
    float* out = (float*)d_out;

    const int B = 16384;
    dim3 grid(B / BPB);   // 1024 blocks
    dim3 block(BLOCK);
    prnn_j2_kernel<<<grid, block, 0, stream>>>(x, W1, W2, out);
}

// Round 3
// 135.011 us; speedup vs baseline: 1.3121x; 1.0488x over previous
//
#include <hip/hip_runtime.h>
#include <math.h>

// PRNN J2 plane-strain elastoplasticity scan.
// B=16384, T=128, F=3, MATPTS=16 (P=262144), O=3.
// Thread = (batch b, material point m). Block = 256 threads = 16 batches.
// R3: fused v_add_f32_dpp reduction (inline asm, hazard-interleaved),
// T-loop unrolled x4 with ds_read_b128 register-double-buffered prefetch,
// LDS row stride padded to 388 (16B aligned, conflict-free b128).

#define BLOCK 256
#define BPB 16              // batch elements per block
#define TSTEPS 128
#define ROWF (TSTEPS * 3)   // 384 floats per batch row
#define ROWP 388            // padded stride: 16B-aligned, group banks {0,4,8,12}

// 16-lane inclusive-scan sum of three registers, single fused DPP add per
// stage, 3-way interleaved => 2 instructions between write and DPP-read of
// the same VGPR (CDNA requires 2 wait states). s_nop 1 covers the hazard
// from the producer FMAs immediately before the block. Lane 15 of each
// row-of-16 ends with the full sum.
#define DPP_REDUCE3(a, b, c)                                                          \
  asm volatile(                                                                       \
    "s_nop 1\n\t"                                                                     \
    "v_add_f32_dpp %0, %0, %0 row_shr:1 row_mask:0xf bank_mask:0xf bound_ctrl:1\n\t"  \
    "v_add_f32_dpp %1, %1, %1 row_shr:1 row_mask:0xf bank_mask:0xf bound_ctrl:1\n\t"  \
    "v_add_f32_dpp %2, %2, %2 row_shr:1 row_mask:0xf bank_mask:0xf bound_ctrl:1\n\t"  \
    "v_add_f32_dpp %0, %0, %0 row_shr:2 row_mask:0xf bank_mask:0xf bound_ctrl:1\n\t"  \
    "v_add_f32_dpp %1, %1, %1 row_shr:2 row_mask:0xf bank_mask:0xf bound_ctrl:1\n\t"  \
    "v_add_f32_dpp %2, %2, %2 row_shr:2 row_mask:0xf bank_mask:0xf bound_ctrl:1\n\t"  \
    "v_add_f32_dpp %0, %0, %0 row_shr:4 row_mask:0xf bank_mask:0xf bound_ctrl:1\n\t"  \
    "v_add_f32_dpp %1, %1, %1 row_shr:4 row_mask:0xf bank_mask:0xf bound_ctrl:1\n\t"  \
    "v_add_f32_dpp %2, %2, %2 row_shr:4 row_mask:0xf bank_mask:0xf bound_ctrl:1\n\t"  \
    "v_add_f32_dpp %0, %0, %0 row_shr:8 row_mask:0xf bank_mask:0xf bound_ctrl:1\n\t"  \
    "v_add_f32_dpp %1, %1, %1 row_shr:8 row_mask:0xf bank_mask:0xf bound_ctrl:1\n\t"  \
    "v_add_f32_dpp %2, %2, %2 row_shr:8 row_mask:0xf bank_mask:0xf bound_ctrl:1"      \
    : "+v"(a), "+v"(b), "+v"(c))

__global__ __launch_bounds__(BLOCK, 4)
void prnn_j2_kernel(const float* __restrict__ x,
                    const float* __restrict__ W1,
                    const float* __restrict__ W2,
                    float* __restrict__ out)
{
    constexpr float MU    = (float)(3130.0 / (2.0 * (1.0 + 0.37)));
    constexpr float LAM   = (float)(3130.0 * 0.37 / ((1.0 + 0.37) * (1.0 - 2.0 * 0.37)));
    constexpr float SIG_Y = 64.8f;
    constexpr float H_ISO = 300.0f;
    const float TWO_MU  = 2.0f * MU;
    const float K3MU    = 3.0f * MU;
    const float INV_DEN = 1.0f / (3.0f * MU + H_ISO);
    const float KBULK   = LAM + TWO_MU * (1.0f / 3.0f);
    const float C_Q2    = 6.0f * MU * MU;

    // +12 floats: allows the harmless one-block-over prefetch on the last iter
    __shared__ float xs[BPB * ROWP + 12];

    const int tid = threadIdx.x;
    const int bl  = tid >> 4;     // local batch index 0..15
    const int m   = tid & 15;     // material point 0..15 == DPP row lane
    const bool m15 = (m == 15);
    const int blockBase = blockIdx.x * (BPB * ROWF);

    // ---- stage x into LDS (coalesced global reads) ----
    for (int i = tid; i < BPB * ROWF; i += BLOCK) {
        int b = i / ROWF;
        int r = i - b * ROWF;
        xs[b * ROWP + r] = x[blockBase + i];
    }

    // ---- per-thread weights (tiny, broadcast through caches) ----
    float w1[3][3], w2s[3][3];
    #pragma unroll
    for (int c = 0; c < 3; ++c)
        #pragma unroll
        for (int f = 0; f < 3; ++f)
            w1[c][f] = W1[(3 * m + c) * 3 + f];
    #pragma unroll
    for (int o = 0; o < 3; ++o)
        #pragma unroll
        for (int c = 0; c < 3; ++c) {
            float w = W2[o * 48 + 3 * m + c];
            w2s[o][c] = fmaxf(w, 0.0f) + log1pf(expf(-fabsf(w)));  // stable softplus
        }

    __syncthreads();

    float p0 = 0.f, p1 = 0.f, p2 = 0.f, p3 = 0.f;
    float yld = SIG_Y;            // running yield threshold SIG_Y + H*alpha
    float* xrow = &xs[bl * ROWP];
    float4* xv  = (float4*)xrow;  // 16B aligned: bl*1552 % 16 == 0

#define J2_STEP(x0_, x1_, x2_, wp_)                                          \
  {                                                                          \
    const float x0 = (x0_), x1 = (x1_), x2 = (x2_);                          \
    const float e0 = w1[0][0]*x0 + w1[0][1]*x1 + w1[0][2]*x2;                \
    const float e1 = w1[1][0]*x0 + w1[1][1]*x1 + w1[1][2]*x2;                \
    const float e2 = w1[2][0]*x0 + w1[2][1]*x1 + w1[2][2]*x2;                \
    const float ee_xx = e0 - p0;                                             \
    const float ee_yy = e1 - p1;                                             \
    const float ee_xy = fmaf(0.5f, e2, -p3);                                 \
    const float tr = (ee_xx + ee_yy) - p2;                                   \
    const float c3 = tr * (1.0f/3.0f);                                       \
    const float exd = ee_xx - c3;                                            \
    const float eyd = ee_yy - c3;                                            \
    const float ezd = -p2 - c3;                                              \
    float u = exd*exd; u = fmaf(eyd, eyd, u); u = fmaf(ezd, ezd, u);         \
    u = fmaf(ee_xy*ee_xy, 2.0f, u);                                          \
    const float q2 = fmaxf(C_Q2 * u, 1e-24f);                                \
    const float rq = __builtin_amdgcn_rsqf(q2);                              \
    const float q  = q2 * rq;                                                \
    const float dgam = fmaxf(q - yld, 0.0f) * INV_DEN;                       \
    yld = fmaf(H_ISO, dgam, yld);                                            \
    const float k   = K3MU * dgam * rq;                                      \
    const float omk = 1.0f - k;                                              \
    const float pm  = KBULK * tr;                                            \
    const float s0 = fmaf(TWO_MU*exd, omk, pm);                              \
    const float s1 = fmaf(TWO_MU*eyd, omk, pm);                              \
    const float s2 = (TWO_MU*ee_xy) * omk;                                   \
    p0 = fmaf(k, exd, p0);                                                   \
    p1 = fmaf(k, eyd, p1);                                                   \
    p2 = fmaf(k, ezd, p2);                                                   \
    p3 = fmaf(k, ee_xy, p3);                                                 \
    float o0 = w2s[0][0]*s0 + w2s[0][1]*s1 + w2s[0][2]*s2;                   \
    float o1 = w2s[1][0]*s0 + w2s[1][1]*s1 + w2s[1][2]*s2;                   \
    float o2 = w2s[2][0]*s0 + w2s[2][1]*s1 + w2s[2][2]*s2;                   \
    DPP_REDUCE3(o0, o1, o2);                                                 \
    if (m15) { (wp_)[0] = o0; (wp_)[1] = o1; (wp_)[2] = o2; }                \
  }

    float4 A = xv[0], Bv = xv[1], Cv = xv[2];
    for (int tb = 0; tb < TSTEPS / 4; ++tb) {
        // prefetch next 4-step block (reads one block past on last iter —
        // lands in the +12 pad, value unused)
        float4 An = xv[3 * tb + 3];
        float4 Bn = xv[3 * tb + 4];
        float4 Cn = xv[3 * tb + 5];

        float* wp = xrow + 12 * tb;
        J2_STEP(A.x, A.y, A.z,  wp + 0);
        J2_STEP(A.w, Bv.x, Bv.y, wp + 3);
        J2_STEP(Bv.z, Bv.w, Cv.x, wp + 6);
        J2_STEP(Cv.y, Cv.z, Cv.w, wp + 9);

        A = An; Bv = Bn; Cv = Cn;
    }
#undef J2_STEP

    __syncthreads();

    // ---- coalesced flush LDS -> out ----
    for (int i = tid; i < BPB * ROWF; i += BLOCK) {
        int b = i / ROWF;
        int r = i - b * ROWF;
        out[blockBase + i] = xs[b * ROWP + r];
    }
}

extern "C" void kernel_launch(void* const* d_in, const int* in_sizes, int n_in,
                              void* d_out, int out_size, void* d_ws, size_t ws_size,
                              hipStream_t stream) {
    const float* x  = (const float*)d_in[0];
    const float* W1 = (const float*)d_in[1];
    const float* W2 = (const float*)d_in[2];
    float* out = (float*)d_out;

    const int B = 16384;
    dim3 grid(B / BPB);   // 1024 blocks
    dim3 block(BLOCK);
    prnn_j2_kernel<<<grid, block, 0, stream>>>(x, W1, W2, out);
}

// Round 4
// 123.000 us; speedup vs baseline: 1.4402x; 1.0977x over previous
//
#include <hip/hip_runtime.h>
#include <math.h>

// PRNN J2 plane-strain elastoplasticity scan.
// B=16384, T=128, F=3, MATPTS=16 (P=262144), O=3.
// R4: packed-FP32 (v_pk_*) — each thread handles TWO material points (m, m+8)
// of one batch as <2 x float>; 8 lanes per batch, 32 batches per 256-thread
// block. Reduction = fold packed halves + 3-stage intra-8 DPP butterfly
// (quad_perm xor1/xor2 + row_half_mirror), all lanes end with the sum.

#define BLOCK 256
#define BPB 32              // batch elements per block (8 lanes each)
#define TSTEPS 128
#define ROWF (TSTEPS * 3)   // 384 floats per batch row
#define ROWP 388            // padded stride: 16B-aligned, /4 for float4

typedef float v2 __attribute__((ext_vector_type(2)));

static __device__ __forceinline__ v2 vfma(v2 a, v2 b, v2 c) {
    return __builtin_elementwise_fma(a, b, c);
}
static __device__ __forceinline__ v2 vmax(v2 a, v2 b) {
    return __builtin_elementwise_max(a, b);
}

// 8-lane butterfly sum of 3 scalars via fused DPP adds. xor1/xor2 are
// intra-quad (quad_perm); cross-quad stage uses row_half_mirror (after the
// first two stages every lane of a quad holds the quad sum, so any lane of
// the other quad is a valid source). 3-way interleave satisfies the 2-wait
// VALU-write->DPP-read hazard; s_nop 1 covers the entry hazard.
#define DPP_BFLY3(a, b, c)                                                       \
  asm volatile(                                                                  \
    "s_nop 1\n\t"                                                                \
    "v_add_f32_dpp %0, %0, %0 quad_perm:[1,0,3,2] row_mask:0xf bank_mask:0xf\n\t"\
    "v_add_f32_dpp %1, %1, %1 quad_perm:[1,0,3,2] row_mask:0xf bank_mask:0xf\n\t"\
    "v_add_f32_dpp %2, %2, %2 quad_perm:[1,0,3,2] row_mask:0xf bank_mask:0xf\n\t"\
    "v_add_f32_dpp %0, %0, %0 quad_perm:[2,3,0,1] row_mask:0xf bank_mask:0xf\n\t"\
    "v_add_f32_dpp %1, %1, %1 quad_perm:[2,3,0,1] row_mask:0xf bank_mask:0xf\n\t"\
    "v_add_f32_dpp %2, %2, %2 quad_perm:[2,3,0,1] row_mask:0xf bank_mask:0xf\n\t"\
    "v_add_f32_dpp %0, %0, %0 row_half_mirror row_mask:0xf bank_mask:0xf\n\t"    \
    "v_add_f32_dpp %1, %1, %1 row_half_mirror row_mask:0xf bank_mask:0xf\n\t"    \
    "v_add_f32_dpp %2, %2, %2 row_half_mirror row_mask:0xf bank_mask:0xf"        \
    : "+v"(a), "+v"(b), "+v"(c))

__global__ __launch_bounds__(BLOCK, 2)
void prnn_j2_kernel(const float* __restrict__ x,
                    const float* __restrict__ W1,
                    const float* __restrict__ W2,
                    float* __restrict__ out)
{
    constexpr float MU    = (float)(3130.0 / (2.0 * (1.0 + 0.37)));
    constexpr float LAM   = (float)(3130.0 * 0.37 / ((1.0 + 0.37) * (1.0 - 2.0 * 0.37)));
    constexpr float SIG_Y = 64.8f;
    constexpr float H_ISO = 300.0f;
    const float TWO_MU  = 2.0f * MU;
    const float K3MU    = 3.0f * MU;
    const float INV_DEN = 1.0f / (3.0f * MU + H_ISO);
    const float KBULK   = LAM + TWO_MU * (1.0f / 3.0f);
    const float C_Q2    = 6.0f * MU * MU;
    const v2 VTHIRD = {1.0f/3.0f, 1.0f/3.0f};
    const v2 VQMIN  = {1e-24f, 1e-24f};
    const v2 VZERO  = {0.0f, 0.0f};

    // +12 floats: harmless one-block-over prefetch on the last iteration
    __shared__ float xs[BPB * ROWP + 12];

    const int tid = threadIdx.x;
    const int bl  = tid >> 3;       // local batch index 0..31
    const int l   = tid & 7;        // lane in 8-group; points (l, l+8)
    const int blockBase = blockIdx.x * (BPB * ROWF);

    // ---- stage x into LDS (coalesced float4 global reads) ----
    {
        const float4* xg = (const float4*)(x + blockBase);
        for (int i4 = tid; i4 < BPB * ROWF / 4; i4 += BLOCK) {
            int b  = i4 / (ROWF / 4);
            int r4 = i4 - b * (ROWF / 4);
            ((float4*)(xs + b * ROWP))[r4] = xg[i4];
        }
    }

    // ---- packed per-thread weights: half .x = point l, half .y = point l+8 ----
    const int pa = l, pb = l + 8;
    v2 w1p[3][3], w2p[3][3];
    #pragma unroll
    for (int c = 0; c < 3; ++c)
        #pragma unroll
        for (int f = 0; f < 3; ++f) {
            w1p[c][f].x = W1[(3 * pa + c) * 3 + f];
            w1p[c][f].y = W1[(3 * pb + c) * 3 + f];
        }
    #pragma unroll
    for (int o = 0; o < 3; ++o)
        #pragma unroll
        for (int c = 0; c < 3; ++c) {
            float wa = W2[o * 48 + 3 * pa + c];
            float wb = W2[o * 48 + 3 * pb + c];
            w2p[o][c].x = fmaxf(wa, 0.0f) + log1pf(expf(-fabsf(wa)));
            w2p[o][c].y = fmaxf(wb, 0.0f) + log1pf(expf(-fabsf(wb)));
        }

    __syncthreads();

    v2 p0 = VZERO, p1 = VZERO, p2 = VZERO, p3 = VZERO;
    v2 yld = {SIG_Y, SIG_Y};
    float* xrow = &xs[bl * ROWP];
    const float4* xv = (const float4*)xrow;   // bl*1552 bytes, 16B aligned

#define J2_STEP(x0_, x1_, x2_, wp_)                                          \
  {                                                                          \
    const float x0s = (x0_), x1s = (x1_), x2s = (x2_);                       \
    const v2 x0 = {x0s, x0s}, x1 = {x1s, x1s}, x2 = {x2s, x2s};              \
    const v2 e0 = vfma(w1p[0][0], x0, vfma(w1p[0][1], x1, w1p[0][2] * x2));  \
    const v2 e1 = vfma(w1p[1][0], x0, vfma(w1p[1][1], x1, w1p[1][2] * x2));  \
    const v2 e2 = vfma(w1p[2][0], x0, vfma(w1p[2][1], x1, w1p[2][2] * x2));  \
    const v2 ee_xx = e0 - p0;                                                \
    const v2 ee_yy = e1 - p1;                                                \
    const v2 ee_xy = 0.5f * e2 - p3;                                         \
    const v2 tr = (ee_xx + ee_yy) - p2;                                      \
    const v2 c3 = tr * VTHIRD;                                               \
    const v2 exd = ee_xx - c3;                                               \
    const v2 eyd = ee_yy - c3;                                               \
    const v2 ezd = -p2 - c3;                                                 \
    v2 u = exd * exd;                                                        \
    u = vfma(eyd, eyd, u);                                                   \
    u = vfma(ezd, ezd, u);                                                   \
    const v2 t2 = ee_xy * ee_xy;                                             \
    u = vfma(t2, (v2){2.0f, 2.0f}, u);                                       \
    const v2 q2 = vmax(C_Q2 * u, VQMIN);                                     \
    v2 rq;                                                                   \
    rq.x = __builtin_amdgcn_rsqf(q2.x);                                      \
    rq.y = __builtin_amdgcn_rsqf(q2.y);                                      \
    const v2 q = q2 * rq;                                                    \
    const v2 dgam = vmax(q - yld, VZERO) * INV_DEN;                          \
    yld = vfma((v2){H_ISO, H_ISO}, dgam, yld);                               \
    const v2 k   = (K3MU * dgam) * rq;                                       \
    const v2 omk = 1.0f - k;                                                 \
    const v2 pm  = KBULK * tr;                                               \
    const v2 s0 = vfma(TWO_MU * exd, omk, pm);                               \
    const v2 s1 = vfma(TWO_MU * eyd, omk, pm);                               \
    const v2 s2 = (TWO_MU * ee_xy) * omk;                                    \
    p0 = vfma(k, exd, p0);                                                   \
    p1 = vfma(k, eyd, p1);                                                   \
    p2 = vfma(k, ezd, p2);                                                   \
    p3 = vfma(k, ee_xy, p3);                                                 \
    v2 q0 = vfma(w2p[0][0], s0, vfma(w2p[0][1], s1, w2p[0][2] * s2));        \
    v2 q1 = vfma(w2p[1][0], s0, vfma(w2p[1][1], s1, w2p[1][2] * s2));        \
    v2 q2o = vfma(w2p[2][0], s0, vfma(w2p[2][1], s1, w2p[2][2] * s2));       \
    float o0 = q0.x + q0.y;                                                  \
    float o1 = q1.x + q1.y;                                                  \
    float o2 = q2o.x + q2o.y;                                                \
    DPP_BFLY3(o0, o1, o2);                                                   \
    if (l < 3) { (wp_)[l] = (l == 0) ? o0 : ((l == 1) ? o1 : o2); }          \
  }

    float4 A = xv[0], Bv = xv[1], Cv = xv[2];
    for (int tb = 0; tb < TSTEPS / 4; ++tb) {
        // prefetch next 4-step block (last iter over-reads into the pad)
        float4 An = xv[3 * tb + 3];
        float4 Bn = xv[3 * tb + 4];
        float4 Cn = xv[3 * tb + 5];

        float* wp = xrow + 12 * tb;
        J2_STEP(A.x,  A.y,  A.z,  wp + 0);
        J2_STEP(A.w,  Bv.x, Bv.y, wp + 3);
        J2_STEP(Bv.z, Bv.w, Cv.x, wp + 6);
        J2_STEP(Cv.y, Cv.z, Cv.w, wp + 9);

        A = An; Bv = Bn; Cv = Cn;
    }
#undef J2_STEP

    __syncthreads();

    // ---- coalesced float4 flush LDS -> out ----
    {
        float4* og = (float4*)(out + blockBase);
        for (int i4 = tid; i4 < BPB * ROWF / 4; i4 += BLOCK) {
            int b  = i4 / (ROWF / 4);
            int r4 = i4 - b * (ROWF / 4);
            og[i4] = ((const float4*)(xs + b * ROWP))[r4];
        }
    }
}

extern "C" void kernel_launch(void* const* d_in, const int* in_sizes, int n_in,
                              void* d_out, int out_size, void* d_ws, size_t ws_size,
                              hipStream_t stream) {
    const float* x  = (const float*)d_in[0];
    const float* W1 = (const float*)d_in[1];
    const float* W2 = (const float*)d_in[2];
    float* out = (float*)d_out;

    const int B = 16384;
    dim3 grid(B / BPB);   // 512 blocks
    dim3 block(BLOCK);
    prnn_j2_kernel<<<grid, block, 0, stream>>>(x, W1, W2, out);
}